// Round 7
// baseline (156.078 us; speedup 1.0000x reference)
//
#include <hip/hip_runtime.h>

#define B_ 2
#define T_ 2048
#define C_ 1024
#define H_ 16
#define D_ 64

using bf16x8 = __attribute__((ext_vector_type(8))) short;
using f32x4  = __attribute__((ext_vector_type(4))) float;

static __device__ __forceinline__ short f2bf(float f) {
  unsigned u = __builtin_bit_cast(unsigned, f);
  unsigned r = u + 0x7fffu + ((u >> 16) & 1u);
  return (short)(r >> 16);
}

#define GLD16(gp, lp) __builtin_amdgcn_global_load_lds( \
    (const __attribute__((address_space(1))) void*)(gp), \
    (__attribute__((address_space(3))) void*)(lp), 16, 0, 0)

// ---------------- cast f32 -> bf16 (vectorized) ----------------
__global__ __launch_bounds__(256) void cast_f32_bf16(const float* __restrict__ in,
                                                     short* __restrict__ out) {
  int i = blockIdx.x * blockDim.x + threadIdx.x;
  float4 v = ((const float4*)in)[i];
  short4 o;
  o.x = f2bf(v.x); o.y = f2bf(v.y); o.z = f2bf(v.z); o.w = f2bf(v.w);
  ((short4*)out)[i] = o;
}

// ---------------- transpose + cast: in [R][N] f32 -> out [N][R] bf16 ----------------
__global__ __launch_bounds__(256) void transpose_cast(const float* __restrict__ in,
                                                      short* __restrict__ out,
                                                      int R, int N) {
  __shared__ float tile[32][33];
  int bx = blockIdx.x * 32, by = blockIdx.y * 32;
  int tx = threadIdx.x, ty = threadIdx.y;
  #pragma unroll
  for (int j = 0; j < 32; j += 8)
    tile[ty + j][tx] = in[(size_t)(by + ty + j) * N + bx + tx];
  __syncthreads();
  #pragma unroll
  for (int j = 0; j < 32; j += 8)
    out[(size_t)(bx + ty + j) * R + by + tx] = f2bf(tile[tx][ty + j]);
}

// ---------------- GEMM: 128x128 tile, BK=64, global_load_lds staging ----------------
// Q prescaled by 0.125*log2(e). V written TRANSPOSED+slot-permuted: Vt[b][h][d][t']
// with t' = within-64 permutation (bit4<->bits3:2 shuffle) matching the PV A-frag
// packing, so attention loads PV B-frags as contiguous 16B.
__global__ __launch_bounds__(256) void gemm_qkv(const short* __restrict__ A,
                                                const short* __restrict__ Bt,
                                                const float* __restrict__ bias,
                                                short* __restrict__ Qo,
                                                short* __restrict__ Ko,
                                                short* __restrict__ Vo) {
  __shared__ short sA[128 * 64];
  __shared__ short sB[128 * 64];
  const int tid = threadIdx.x;
  const int w = tid >> 6, lane = tid & 63;
  const int wm = w >> 1, wn = w & 1;
  const int g = lane >> 4, r16 = lane & 15;
  const int m0 = blockIdx.x * 128, n0 = blockIdx.y * 128;
  const int krow = lane >> 3, kslot = lane & 7;

  f32x4 acc[4][4] = {};

  for (int k0 = 0; k0 < 1024; k0 += 64) {
    __syncthreads();
    #pragma unroll
    for (int p = 0; p < 4; ++p) {
      int rbase = w * 32 + p * 8;
      int row = rbase + krow;
      GLD16(&A[(size_t)(m0 + row) * 1024 + k0 + ((kslot ^ (row & 7)) * 8)], &sA[rbase * 64]);
      GLD16(&Bt[(size_t)(n0 + row) * 1024 + k0 + ((kslot ^ (row & 7)) * 8)], &sB[rbase * 64]);
    }
    __syncthreads();
    bf16x8 af[4][2], bf[4][2];
    #pragma unroll
    for (int mi = 0; mi < 4; ++mi) {
      int row = wm * 64 + mi * 16 + r16;
      #pragma unroll
      for (int c = 0; c < 2; ++c)
        af[mi][c] = *(const bf16x8*)&sA[row * 64 + (((c * 4 + g) ^ (row & 7)) * 8)];
    }
    #pragma unroll
    for (int ni = 0; ni < 4; ++ni) {
      int row = wn * 64 + ni * 16 + r16;
      #pragma unroll
      for (int c = 0; c < 2; ++c)
        bf[ni][c] = *(const bf16x8*)&sB[row * 64 + (((c * 4 + g) ^ (row & 7)) * 8)];
    }
    __builtin_amdgcn_s_setprio(1);
    #pragma unroll
    for (int mi = 0; mi < 4; ++mi)
      #pragma unroll
      for (int ni = 0; ni < 4; ++ni) {
        acc[mi][ni] = __builtin_amdgcn_mfma_f32_16x16x32_bf16(af[mi][0], bf[ni][0], acc[mi][ni], 0, 0, 0);
        acc[mi][ni] = __builtin_amdgcn_mfma_f32_16x16x32_bf16(af[mi][1], bf[ni][1], acc[mi][ni], 0, 0, 0);
      }
    __builtin_amdgcn_s_setprio(0);
  }

  #pragma unroll
  for (int mi = 0; mi < 4; ++mi) {
    #pragma unroll
    for (int ni = 0; ni < 4; ++ni) {
      int n = n0 + wn * 64 + ni * 16 + r16;
      float bv = bias[n];
      int which = n >> 10;
      int c = n & 1023;
      int hh = c >> 6, d = c & 63;
      float sc = (which == 0) ? 0.18033688f : 1.0f;  // 0.125 * log2(e) folded into Q
      #pragma unroll
      for (int rr = 0; rr < 4; ++rr) {
        int m = m0 + wm * 64 + mi * 16 + g * 4 + rr;
        int b = m >> 11, t = m & 2047;
        short val = f2bf((acc[mi][ni][rr] + bv) * sc);
        if (which == 2) {
          // slot-permute t within its 64-block: bit4 -> bit2, bits3:2 -> bits4:3
          int tp = (t & ~0x1C) | ((t & 0xC) << 1) | ((t & 0x10) >> 2);
          Vo[(size_t)((b * H_ + hh) * D_ + d) * T_ + tp] = val;
        } else {
          short* dst = (which == 0) ? Qo : Ko;
          dst[(size_t)((b * H_ + hh) * T_ + t) * D_ + d] = val;
        }
      }
    }
  }
}

__global__ __launch_bounds__(256) void gemm_out(const short* __restrict__ A,
                                                const short* __restrict__ Bt,
                                                const float* __restrict__ bias,
                                                float* __restrict__ Out) {
  __shared__ short sA[128 * 64];
  __shared__ short sB[128 * 64];
  const int tid = threadIdx.x;
  const int w = tid >> 6, lane = tid & 63;
  const int wm = w >> 1, wn = w & 1;
  const int g = lane >> 4, r16 = lane & 15;
  const int m0 = blockIdx.x * 128, n0 = blockIdx.y * 128;
  const int krow = lane >> 3, kslot = lane & 7;

  f32x4 acc[4][4] = {};

  for (int k0 = 0; k0 < 1024; k0 += 64) {
    __syncthreads();
    #pragma unroll
    for (int p = 0; p < 4; ++p) {
      int rbase = w * 32 + p * 8;
      int row = rbase + krow;
      GLD16(&A[(size_t)(m0 + row) * 1024 + k0 + ((kslot ^ (row & 7)) * 8)], &sA[rbase * 64]);
      GLD16(&Bt[(size_t)(n0 + row) * 1024 + k0 + ((kslot ^ (row & 7)) * 8)], &sB[rbase * 64]);
    }
    __syncthreads();
    bf16x8 af[4][2], bf[4][2];
    #pragma unroll
    for (int mi = 0; mi < 4; ++mi) {
      int row = wm * 64 + mi * 16 + r16;
      #pragma unroll
      for (int c = 0; c < 2; ++c)
        af[mi][c] = *(const bf16x8*)&sA[row * 64 + (((c * 4 + g) ^ (row & 7)) * 8)];
    }
    #pragma unroll
    for (int ni = 0; ni < 4; ++ni) {
      int row = wn * 64 + ni * 16 + r16;
      #pragma unroll
      for (int c = 0; c < 2; ++c)
        bf[ni][c] = *(const bf16x8*)&sB[row * 64 + (((c * 4 + g) ^ (row & 7)) * 8)];
    }
    __builtin_amdgcn_s_setprio(1);
    #pragma unroll
    for (int mi = 0; mi < 4; ++mi)
      #pragma unroll
      for (int ni = 0; ni < 4; ++ni) {
        acc[mi][ni] = __builtin_amdgcn_mfma_f32_16x16x32_bf16(af[mi][0], bf[ni][0], acc[mi][ni], 0, 0, 0);
        acc[mi][ni] = __builtin_amdgcn_mfma_f32_16x16x32_bf16(af[mi][1], bf[ni][1], acc[mi][ni], 0, 0, 0);
      }
    __builtin_amdgcn_s_setprio(0);
  }

  #pragma unroll
  for (int mi = 0; mi < 4; ++mi) {
    #pragma unroll
    for (int ni = 0; ni < 4; ++ni) {
      int n = n0 + wn * 64 + ni * 16 + r16;
      float bv = bias[n];
      #pragma unroll
      for (int rr = 0; rr < 4; ++rr) {
        int m = m0 + wm * 64 + mi * 16 + g * 4 + rr;
        Out[(size_t)m * 1024 + n] = acc[mi][ni][rr] + bv;
      }
    }
  }
}

// ---------------- flash attention: ZERO LDS, ZERO barriers ----------------
// grid (bh=32, 32), 128 threads = 2 independent waves. Wave owns 32 q-rows
// (2 strips of 16 sharing every K/V fragment). All operands are contiguous 16B
// global loads (K direct; V from permuted-transposed Vt). Swapped mfma(K,Q)
// softmax fully in-register; packed P feeds PV directly. Waves never sync ->
// full latency hiding via TLP + compiler pipelining (kf prefetched 1 tile ahead).
__global__ __launch_bounds__(128, 2) void attn_fwd(const short* __restrict__ Q,
                                                   const short* __restrict__ K,
                                                   const short* __restrict__ Vt,
                                                   short* __restrict__ O) {
  const int tid = threadIdx.x;
  const int w = tid >> 6, lane = tid & 63;
  const int g = lane >> 4, r16 = lane & 15;
  const int bh = blockIdx.x;
  const int b = bh >> 4, hh = bh & 15;
  const int qt = 31 - (int)blockIdx.y;    // LPT: heavy first
  const int qs = qt * 64 + w * 32;        // wave's 32-row strip base

  const short* Qh = Q + (size_t)bh * T_ * D_;
  const short* Kh = K + (size_t)bh * T_ * D_;
  const short* Vh = Vt + (size_t)bh * D_ * T_;   // [d][t'] permuted

  // Q fragments: strips u=0,1 (rows qs+u*16+r16)
  bf16x8 qf[2][2];
  #pragma unroll
  for (int u = 0; u < 2; ++u) {
    const size_t qoff = (size_t)(qs + u * 16 + r16) * 64;
    qf[u][0] = *(const bf16x8*)&Qh[qoff + g * 8];
    qf[u][1] = *(const bf16x8*)&Qh[qoff + 32 + g * 8];
  }

  f32x4 o[2][4] = {};
  float m_[2] = {-1e30f, -1e30f}, l_[2] = {0.f, 0.f};

  const int nkt = qs / 64 + 1;

  // prologue: kf(0)
  bf16x8 kf[4][2];
  #pragma unroll
  for (int nt = 0; nt < 4; ++nt) {
    const size_t koff = (size_t)(nt * 16 + r16) * 64;
    kf[nt][0] = *(const bf16x8*)&Kh[koff + g * 8];
    kf[nt][1] = *(const bf16x8*)&Kh[koff + 32 + g * 8];
  }

  for (int kt = 0; kt < nkt; ++kt) {
    const int k0 = kt * 64;

    // ---- issue V(kt) loads (consumed after softmax) ----
    bf16x8 vb[4][2];
    #pragma unroll
    for (int nt = 0; nt < 4; ++nt) {
      const size_t voff = (size_t)(nt * 16 + r16) * T_ + k0;
      vb[nt][0] = *(const bf16x8*)&Vh[voff + g * 8];
      vb[nt][1] = *(const bf16x8*)&Vh[voff + 32 + g * 8];
    }

    // ---- S^T = K Q^T : lane holds S[key = nt*16+4g+rr][q = r16] per strip ----
    f32x4 s[2][4] = {};
    __builtin_amdgcn_s_setprio(1);
    #pragma unroll
    for (int nt = 0; nt < 4; ++nt) {
      s[0][nt] = __builtin_amdgcn_mfma_f32_16x16x32_bf16(kf[nt][0], qf[0][0], s[0][nt], 0, 0, 0);
      s[0][nt] = __builtin_amdgcn_mfma_f32_16x16x32_bf16(kf[nt][1], qf[0][1], s[0][nt], 0, 0, 0);
      s[1][nt] = __builtin_amdgcn_mfma_f32_16x16x32_bf16(kf[nt][0], qf[1][0], s[1][nt], 0, 0, 0);
      s[1][nt] = __builtin_amdgcn_mfma_f32_16x16x32_bf16(kf[nt][1], qf[1][1], s[1][nt], 0, 0, 0);
    }
    __builtin_amdgcn_s_setprio(0);

    // ---- prefetch K(kt+1) while softmax runs ----
    if (kt + 1 < nkt) {
      const int k1 = k0 + 64;
      #pragma unroll
      for (int nt = 0; nt < 4; ++nt) {
        const size_t koff = (size_t)(k1 + nt * 16 + r16) * 64;
        kf[nt][0] = *(const bf16x8*)&Kh[koff + g * 8];
        kf[nt][1] = *(const bf16x8*)&Kh[koff + 32 + g * 8];
      }
    }

    // ---- online softmax per strip (log2 domain; Q prescaled) ----
    bf16x8 pa[2][2];
    #pragma unroll
    for (int u = 0; u < 2; ++u) {
      if (kt == nkt - 1) {  // diagonal tile
        const int qrow = qs + u * 16 + r16;
        #pragma unroll
        for (int nt = 0; nt < 4; ++nt)
          #pragma unroll
          for (int rr = 0; rr < 4; ++rr)
            if (k0 + nt * 16 + 4 * g + rr > qrow) s[u][nt][rr] = -1e30f;
      }
      float pmax = s[u][0][0];
      #pragma unroll
      for (int nt = 0; nt < 4; ++nt)
        #pragma unroll
        for (int rr = 0; rr < 4; ++rr)
          pmax = fmaxf(pmax, s[u][nt][rr]);
      pmax = fmaxf(pmax, __shfl_xor(pmax, 16));
      pmax = fmaxf(pmax, __shfl_xor(pmax, 32));
      if (!__all(pmax - m_[u] <= 8.0f)) {  // defer-max (T13)
        float mn = fmaxf(m_[u], pmax);
        float al = __builtin_amdgcn_exp2f(m_[u] - mn);
        m_[u] = mn;
        l_[u] *= al;
        float av[4];
        #pragma unroll
        for (int rr = 0; rr < 4; ++rr) av[rr] = __shfl(al, 4 * g + rr, 16);
        #pragma unroll
        for (int nt = 0; nt < 4; ++nt)
          #pragma unroll
          for (int rr = 0; rr < 4; ++rr) o[u][nt][rr] *= av[rr];
      }
      float rs = 0.f;
      #pragma unroll
      for (int nt = 0; nt < 4; ++nt)
        #pragma unroll
        for (int rr = 0; rr < 4; ++rr) {
          float p = __builtin_amdgcn_exp2f(s[u][nt][rr] - m_[u]);
          s[u][nt][rr] = p;
          rs += p;
        }
      rs += __shfl_xor(rs, 16);
      rs += __shfl_xor(rs, 32);
      l_[u] += rs;
      int pk[8];
      #pragma unroll
      for (int nt = 0; nt < 4; ++nt)
        #pragma unroll
        for (int h = 0; h < 2; ++h)
          asm("v_cvt_pk_bf16_f32 %0, %1, %2"
              : "=v"(pk[nt * 2 + h])
              : "v"(s[u][nt][2 * h]), "v"(s[u][nt][2 * h + 1]));
      int4 t0; t0.x = pk[0]; t0.y = pk[1]; t0.z = pk[2]; t0.w = pk[3];
      int4 t1; t1.x = pk[4]; t1.y = pk[5]; t1.z = pk[6]; t1.w = pk[7];
      pa[u][0] = __builtin_bit_cast(bf16x8, t0);
      pa[u][1] = __builtin_bit_cast(bf16x8, t1);
    }

    // ---- O += P @ V (vb slot-permuted to match pa packing) ----
    __builtin_amdgcn_s_setprio(1);
    #pragma unroll
    for (int nt = 0; nt < 4; ++nt) {
      o[0][nt] = __builtin_amdgcn_mfma_f32_16x16x32_bf16(pa[0][0], vb[nt][0], o[0][nt], 0, 0, 0);
      o[0][nt] = __builtin_amdgcn_mfma_f32_16x16x32_bf16(pa[0][1], vb[nt][1], o[0][nt], 0, 0, 0);
      o[1][nt] = __builtin_amdgcn_mfma_f32_16x16x32_bf16(pa[1][0], vb[nt][0], o[1][nt], 0, 0, 0);
      o[1][nt] = __builtin_amdgcn_mfma_f32_16x16x32_bf16(pa[1][1], vb[nt][1], o[1][nt], 0, 0, 0);
    }
    __builtin_amdgcn_s_setprio(0);
  }

  // ---- epilogue: O /= l ----
  #pragma unroll
  for (int u = 0; u < 2; ++u) {
    float lv[4];
    #pragma unroll
    for (int rr = 0; rr < 4; ++rr) lv[rr] = __shfl(l_[u], 4 * g + rr, 16);
    #pragma unroll
    for (int nt = 0; nt < 4; ++nt) {
      int d = nt * 16 + r16;
      #pragma unroll
      for (int rr = 0; rr < 4; ++rr) {
        int t = qs + u * 16 + 4 * g + rr;
        O[(size_t)(b * T_ + t) * C_ + hh * 64 + d] = f2bf(o[u][nt][rr] / lv[rr]);
      }
    }
  }
}

extern "C" void kernel_launch(void* const* d_in, const int* in_sizes, int n_in,
                              void* d_out, int out_size, void* d_ws, size_t ws_size,
                              hipStream_t stream) {
  const float* x     = (const float*)d_in[0];
  const float* w_qkv = (const float*)d_in[1];
  const float* b_qkv = (const float*)d_in[2];
  const float* w_out = (const float*)d_in[3];
  const float* b_out = (const float*)d_in[4];
  float* out = (float*)d_out;

  char* ws = (char*)d_ws;
  if (ws_size < (size_t)(40u << 20)) return;

  short* xb     = (short*)(ws);                        // 8 MiB  [4096][1024] bf16
  short* wqkvT  = (short*)(ws + ((size_t)8u << 20));   // 6 MiB  [3072][1024] bf16
  short* woutT  = (short*)(ws + ((size_t)14u << 20));  // 2 MiB  [1024][1024] bf16
  short* Qb     = (short*)(ws + ((size_t)16u << 20));  // 8 MiB  [B][H][T][D] (prescaled)
  short* Kb     = (short*)(ws + ((size_t)24u << 20));  // 8 MiB  [B][H][T][D]
  short* Vtb    = (short*)(ws + ((size_t)32u << 20));  // 8 MiB  [B][H][D][T'] permuted
  short* attn_o = xb;  // xb dead after gemm_qkv

  cast_f32_bf16<<<4096, 256, 0, stream>>>(x, xb);
  transpose_cast<<<dim3(96, 32), dim3(32, 8), 0, stream>>>(w_qkv, wqkvT, 1024, 3072);
  transpose_cast<<<dim3(32, 32), dim3(32, 8), 0, stream>>>(w_out, woutT, 1024, 1024);
  gemm_qkv<<<dim3(32, 24), 256, 0, stream>>>(xb, wqkvT, b_qkv, Qb, Kb, Vtb);
  attn_fwd<<<dim3(32, 32), 128, 0, stream>>>(Qb, Kb, Vtb, attn_o);
  gemm_out<<<dim3(32, 8), 256, 0, stream>>>(attn_o, woutT, b_out, out);
}